// Round 2
// baseline (163.022 us; speedup 1.0000x reference)
//
#include <hip/hip_runtime.h>
#include <hip/hip_bf16.h>

// HeteroLinear: out[b,n,o] = sum_i x[b,n,i] * W[t[n]][o][i] + bias[t[n]][o]
// B=16, N=16384, F_IN=F_OUT=128, NUM_TYPES=16, fp32 in/out.
//
// Round 2: bucket nodes by type so W[t] is staged once per block in LDS
// (bf16, XOR-swizzled), removing the per-wave W re-read from L2 that made
// round 1 latency-bound. x accuracy kept via hi/lo bf16 split (2 MFMAs).

#define NN 16384
#define FF 128
#define NT 16
#define NPB 16   // nodes per main-kernel block (4 waves x 4 nodes)

typedef __bf16 bf16x8 __attribute__((ext_vector_type(8)));
typedef float  f32x4  __attribute__((ext_vector_type(4)));

// ws int layout: [0:16) count, [16:32) off, [32:48) cursor, [64:64+NN) order

__global__ void hl_init(int* ws) {
    if (threadIdx.x < 48) ws[threadIdx.x] = 0;
}

__global__ void hl_count(const int* __restrict__ tv, int* __restrict__ ws) {
    int n = blockIdx.x * 256 + threadIdx.x;
    atomicAdd(&ws[tv[n]], 1);
}

__global__ void hl_offsets(int* ws) {
    if (threadIdx.x == 0) {
        int acc = 0;
        for (int t = 0; t < NT; ++t) { ws[16 + t] = acc; acc += ws[t]; }
    }
}

__global__ void hl_scatter(const int* __restrict__ tv, int* __restrict__ ws) {
    int n = blockIdx.x * 256 + threadIdx.x;
    int t = tv[n];
    int pos = atomicAdd(&ws[32 + t], 1);
    ws[64 + ws[16 + t] + pos] = n;
}

__global__ __launch_bounds__(256) void hl_main(
    const float* __restrict__ x,      // [16][NN][128]
    const float* __restrict__ W,      // [16][128][128]
    const float* __restrict__ bias,   // [16][128]
    const int*   __restrict__ ws,
    float*       __restrict__ out)    // [16][NN][128]
{
    const int t     = blockIdx.x;
    const int cnt   = ws[t];
    const int start = blockIdx.y * NPB;
    if (start >= cnt) return;
    const int base   = ws[16 + t] + start;
    const int nnodes = min(NPB, cnt - start);

    // W[t] as bf16, row-major [o][k], 256B/row, XOR-swizzled 16B slots.
    __shared__ __align__(16) unsigned char Wl[FF * 256];

    const float* Wt = W + t * (FF * FF);
    for (int idx = threadIdx.x; idx < 2048; idx += 256) {   // 8 floats per chunk
        const float* p = Wt + idx * 8;
        f32x4 a = *(const f32x4*)p;
        f32x4 b = *(const f32x4*)(p + 4);
        bf16x8 v;
#pragma unroll
        for (int j = 0; j < 4; ++j) { v[j] = (__bf16)a[j]; v[4 + j] = (__bf16)b[j]; }
        const int o  = idx >> 4;           // row
        const int cb = (idx & 15) << 4;    // byte col within row
        *(bf16x8*)(Wl + o * 256 + (cb ^ ((o & 7) << 4))) = v;
    }
    __syncthreads();

    const int lane = threadIdx.x & 63;
    const int wv   = threadIdx.x >> 6;
    const int lrow = lane & 15;   // A row (b) / B col (o) / D col (o)
    const int lgrp = lane >> 4;   // k-group of 8 / D row-group

    float bv[8];
#pragma unroll
    for (int ot = 0; ot < 8; ++ot) bv[ot] = bias[t * FF + ot * 16 + lrow];

    const int* order = ws + 64;
    for (int i = wv; i < nnodes; i += 4) {
        const int n = order[base + i];
        const float* xp = x + (size_t)lrow * ((size_t)NN * FF) + (size_t)n * FF + lgrp * 8;

        f32x4 xv[8];
#pragma unroll
        for (int kk = 0; kk < 4; ++kk) {
            xv[2 * kk]     = *(const f32x4*)(xp + kk * 32);
            xv[2 * kk + 1] = *(const f32x4*)(xp + kk * 32 + 4);
        }
        bf16x8 ahi[4], alo[4];
#pragma unroll
        for (int kk = 0; kk < 4; ++kk) {
#pragma unroll
            for (int j = 0; j < 4; ++j) {
                const float f0 = xv[2 * kk][j], f1 = xv[2 * kk + 1][j];
                const __bf16 h0 = (__bf16)f0, h1 = (__bf16)f1;
                ahi[kk][j]     = h0;  alo[kk][j]     = (__bf16)(f0 - (float)h0);
                ahi[kk][4 + j] = h1;  alo[kk][4 + j] = (__bf16)(f1 - (float)h1);
            }
        }

        f32x4 acc[8];
#pragma unroll
        for (int ot = 0; ot < 8; ++ot) acc[ot] = (f32x4){0.f, 0.f, 0.f, 0.f};

#pragma unroll
        for (int kk = 0; kk < 4; ++kk) {
#pragma unroll
            for (int ot = 0; ot < 8; ++ot) {
                const int o  = ot * 16 + lrow;
                const int cb = (kk * 64 + lgrp * 16) ^ ((o & 7) << 4);
                const bf16x8 wf = *(const bf16x8*)(Wl + o * 256 + cb);
                acc[ot] = __builtin_amdgcn_mfma_f32_16x16x32_bf16(ahi[kk], wf, acc[ot], 0, 0, 0);
                acc[ot] = __builtin_amdgcn_mfma_f32_16x16x32_bf16(alo[kk], wf, acc[ot], 0, 0, 0);
            }
        }

#pragma unroll
        for (int ot = 0; ot < 8; ++ot) {
            const int o = ot * 16 + lrow;
#pragma unroll
            for (int r = 0; r < 4; ++r) {
                out[(size_t)(lgrp * 4 + r) * ((size_t)NN * FF) + (size_t)n * FF + o]
                    = acc[ot][r] + bv[ot];
            }
        }
    }
}

extern "C" void kernel_launch(void* const* d_in, const int* in_sizes, int n_in,
                              void* d_out, int out_size, void* d_ws, size_t ws_size,
                              hipStream_t stream) {
    const float* x    = (const float*)d_in[0];
    const int*   tv   = (const int*)d_in[1];
    const float* W    = (const float*)d_in[2];
    const float* bias = (const float*)d_in[3];
    float*       out  = (float*)d_out;
    int*         wsI  = (int*)d_ws;

    hl_init<<<1, 64, 0, stream>>>(wsI);
    hl_count<<<NN / 256, 256, 0, stream>>>(tv, wsI);
    hl_offsets<<<1, 64, 0, stream>>>(wsI);
    hl_scatter<<<NN / 256, 256, 0, stream>>>(tv, wsI);
    hl_main<<<dim3(NT, NN / NPB), 256, 0, stream>>>(x, W, bias, wsI, out);
}